// Round 13
// baseline (141.697 us; speedup 1.0000x reference)
//
#include <hip/hip_runtime.h>
#include <hip/hip_bf16.h>
#include <stdint.h>

typedef __bf16 bf16_t;
typedef float floatx4 __attribute__((ext_vector_type(4)));
typedef __bf16 bf16x8 __attribute__((ext_vector_type(8)));
typedef __bf16 bf16x4 __attribute__((ext_vector_type(4)));
typedef unsigned int uintx4 __attribute__((ext_vector_type(4)));

// scale = DH^-0.5 * log2(e), folded into Q at GEMM epilogue so softmax uses raw exp2
#define QSCALE 0.1803368801111204f

// -------------------- async global->LDS (16B) --------------------
__device__ __forceinline__ void gl2lds16(const bf16_t* g, bf16_t* l) {
    __builtin_amdgcn_global_load_lds(
        (const __attribute__((address_space(1))) unsigned int*)g,
        (__attribute__((address_space(3))) unsigned int*)l,
        16, 0, 0);
}

// pack two f32 -> one dword of 2 bf16
__device__ __forceinline__ unsigned pk2(float lo, float hi) {
    unsigned short a = __builtin_bit_cast(unsigned short, (bf16_t)lo);
    unsigned short b = __builtin_bit_cast(unsigned short, (bf16_t)hi);
    return (unsigned)a | ((unsigned)b << 16);
}

// -------------------- fp32 -> bf16 convert (x and W fused) --------------------
__global__ __launch_bounds__(256) void convert_kernel(const float* __restrict__ x,
                                                      bf16_t* __restrict__ xb,
                                                      const float* __restrict__ w,
                                                      bf16_t* __restrict__ wb,
                                                      int nx4) {   // x chunks; W chunks follow
    int i = blockIdx.x * 256 + threadIdx.x;
    const float* in; bf16_t* out; int j;
    if (i < nx4) { in = x; out = xb; j = i; }
    else         { in = w; out = wb; j = i - nx4; }
    float4 v = ((const float4*)in)[j];
    bf16x4 o;
    o.x = (bf16_t)v.x; o.y = (bf16_t)v.y; o.z = (bf16_t)v.z; o.w = (bf16_t)v.w;
    ((bf16x4*)out)[j] = o;
}

// -------------------- QKV projection GEMM (gemm_bt) --------------------
// R10 structure (session best) — byte-identical to the 140.6us config.
__global__ __launch_bounds__(256, 3) void qkv_gemm(const bf16_t* __restrict__ X,   // [8192][512]
                                                   const bf16_t* __restrict__ W,   // [1536][512]
                                                   bf16_t* __restrict__ Q,         // [32][2048][64] (pre-scaled)
                                                   bf16_t* __restrict__ K,         // [32][2048][64]
                                                   bf16_t* __restrict__ Vt)        // [32][64][2048]
{
    __shared__ bf16_t As[2][128 * 64];   // 2 x 16 KB
    __shared__ bf16_t Bs[2][64 * 64];    // 2 x  8 KB   (total 48 KB -> 3 blocks/CU)

    const int tid  = threadIdx.x;
    const int wave = tid >> 6;
    const int lane = tid & 63;
    const int quad = lane >> 4;
    const int lrow = lane & 15;
    const int t7g  = lrow & 7;      // = row&7 of every fragment row this lane touches
    const int wbase = tid & 192;    // wave*64, wave-uniform

    int raw = blockIdx.x;
    int xcd = raw & 7;
    int idx = raw >> 3;
    int bx  = xcd * 8 + idx / 24;
    int by  = idx - (idx / 24) * 24;
    const int bm0 = bx * 128;
    const int bn0 = by * 64;
    const int mw = (wave >> 1) * 64;
    const int nw = (wave & 1) * 32;

    floatx4 acc[4][2];
#pragma unroll
    for (int i = 0; i < 4; i++)
#pragma unroll
        for (int j = 0; j < 2; j++) acc[i][j] = (floatx4)0.0f;

    const bf16_t* xb  = X + (size_t)bm0 * 512;
    const bf16_t* wbp = W + (size_t)bn0 * 512;
    const bf16_t* srcA[4];
    const bf16_t* srcB[2];
#pragma unroll
    for (int r = 0; r < 4; ++r) {
        int c = r * 256 + tid;
        int row = c >> 3, kc = c & 7;
        int skc = kc ^ (row & 7);              // swizzled source chunk
        srcA[r] = xb + (size_t)row * 512 + skc * 8;
    }
#pragma unroll
    for (int r = 0; r < 2; ++r) {
        int c = r * 256 + tid;
        int row = c >> 3, kc = c & 7;
        int skc = kc ^ (row & 7);
        srcB[r] = wbp + (size_t)row * 512 + skc * 8;
    }

    auto STAGE = [&](int bufI, int k0) {
#pragma unroll
        for (int r = 0; r < 4; ++r)
            gl2lds16(srcA[r] + k0, As[bufI] + (size_t)(r * 256 + wbase) * 8);
#pragma unroll
        for (int r = 0; r < 2; ++r)
            gl2lds16(srcB[r] + k0, Bs[bufI] + (size_t)(r * 256 + wbase) * 8);
    };

    STAGE(0, 0);

#pragma unroll 1
    for (int kb = 0; kb < 8; ++kb) {
        const int buf = kb & 1;
        __syncthreads();                 // drains vmcnt: tile kb staged; prev compute done
        if (kb < 7) STAGE(buf ^ 1, (kb + 1) * 64);

        const bf16_t* as = As[buf];
        const bf16_t* bs = Bs[buf];
#pragma unroll
        for (int ks = 0; ks < 2; ++ks) {
            bf16x8 af[4], bfr[2];
#pragma unroll
            for (int mi = 0; mi < 4; mi++)
                af[mi] = *(const bf16x8*)(as + (mw + mi * 16 + lrow) * 64 + (((ks * 4 + quad) ^ t7g) << 3));
#pragma unroll
            for (int ni = 0; ni < 2; ni++)
                bfr[ni] = *(const bf16x8*)(bs + (nw + ni * 16 + lrow) * 64 + (((ks * 4 + quad) ^ t7g) << 3));
            __builtin_amdgcn_s_setprio(1);
#pragma unroll
            for (int mi = 0; mi < 4; mi++)
#pragma unroll
                for (int ni = 0; ni < 2; ni++)
                    acc[mi][ni] = __builtin_amdgcn_mfma_f32_16x16x32_bf16(af[mi], bfr[ni], acc[mi][ni], 0, 0, 0);
            __builtin_amdgcn_s_setprio(0);
        }
    }

    // epilogue: C/D layout col=lane&15, row=quad*4+reg  [verified m89]
#pragma unroll
    for (int mi = 0; mi < 4; mi++) {
        int mbase = bm0 + mw + mi * 16 + quad * 4;
        int b = mbase >> 11, n = mbase & 2047;
#pragma unroll
        for (int ni = 0; ni < 2; ni++) {
            int o = bn0 + nw + ni * 16 + lrow;
            int s  = o >> 9;
            int h  = (o >> 6) & 7;
            int dh = o & 63;
            int bh = b * 8 + h;
            if (s == 2) {
                bf16x4 pv;
#pragma unroll
                for (int r = 0; r < 4; r++) pv[r] = (bf16_t)acc[mi][ni][r];
                *(bf16x4*)(Vt + ((size_t)bh * 64 + dh) * 2048 + n) = pv;   // 8B packed
            } else if (s == 0) {
#pragma unroll
                for (int r = 0; r < 4; r++)
                    Q[((size_t)bh * 2048 + n + r) * 64 + dh] = (bf16_t)(acc[mi][ni][r] * QSCALE);
            } else {
#pragma unroll
                for (int r = 0; r < 4; r++)
                    K[((size_t)bh * 2048 + n + r) * 64 + dh] = (bf16_t)acc[mi][ni][r];
            }
        }
    }
}

// -------------------- flash attention --------------------
// R17 = R8 structure + T15 cross-iteration PV pipeline. Mechanism (m114/m214):
// MFMA and VALU/trans are separate pipes; R8's per-kt chain QK^T -> exp2/pack
// -> PV leaves the matrix pipe idle during the ~300cy softmax window. Carry
// pfragP+vfP in registers across the barrier and run PV(kt-1) (pure-reg
// MFMAs) interleaved with QK^T(kt)/exp2(kt). vfP ds_reads issue at iteration
// end; their lgkm wait is absorbed by the barrier's own lgkmcnt(0) drain.
// Prologue branchless: pfragP=vfP=0 -> PV(-1) adds 0. Tail PV(31) after loop.
// Hazards: vfP are registers (immune to buffer overwrite); own-wave ds_reads
// drain at barrier entry before any wave can issue stage(kt+2) into buf. OK.
__device__ __forceinline__ void stage_tile(const bf16_t* __restrict__ kb,
                                           const bf16_t* __restrict__ vb,
                                           int kt, bf16_t* ksbuf, bf16_t* vsbuf,
                                           int wave, int lane) {
#pragma unroll
    for (int part = 0; part < 2; ++part) {
        int ch  = part * 256 + wave * 64 + lane;   // chunk id 0..511
        int row = ch >> 3, cc = ch & 7;
        int scc = cc ^ (row & 7);                  // swizzled source chunk
        bf16_t* ldst = ksbuf + (size_t)(part * 256 + wave * 64) * 8;  // wave-uniform
        gl2lds16(kb + ((size_t)(kt * 64 + row)) * 64 + scc * 8, ldst);
        bf16_t* ldst2 = vsbuf + (size_t)(part * 256 + wave * 64) * 8;
        gl2lds16(vb + (size_t)row * 2048 + kt * 64 + scc * 8, ldst2);
    }
}

__global__ __launch_bounds__(256, 4) void flash_attn(const bf16_t* __restrict__ Q,   // [32][2048][64], pre-scaled
                                                     const bf16_t* __restrict__ K,   // [32][2048][64]
                                                     const bf16_t* __restrict__ Vt,  // [32][64][2048]
                                                     float* __restrict__ Out)        // [4][2048][512]
{
    __shared__ bf16_t Ks[2][64 * 64];   // 16 KB
    __shared__ bf16_t Vs[2][64 * 64];   // 16 KB
    // total 32768 B; grid = 4 blocks/CU (1024 blocks / 256 CU)

    const int tid  = threadIdx.x;
    const int wave = tid >> 6;
    const int lane = tid & 63;
    const int quad = lane >> 4;
    const int c    = lane & 15;
    const int t7   = c & 7;
    const int qhalf = wave >> 1;   // which 32 q-rows
    const int khalf = wave & 1;    // which 32 keys of each 64-key tile
    const int qt = blockIdx.x;
    const int bh = blockIdx.y;
    const int b = bh >> 3, h = bh & 7;

    // K A-operand row map: m=c -> key row bw = quad-bit-swapped c (bijective 0..15)
    const int bw    = ((c & 4) << 1) | ((c & 8) >> 1) | (c & 3);
    const int brow7 = bw & 7;

    // Q fragments (B-operand: n=lane&15=q-col, k=quad*8+j), shifted-query source row.
    bf16x8 qf[2][2];
#pragma unroll
    for (int mt = 0; mt < 2; ++mt) {
        int qg  = qt * 64 + qhalf * 32 + mt * 16 + c;
        int src = (qg == 0) ? 0 : qg - 1;
        const bf16_t* qbase = Q + ((size_t)bh * 2048 + src) * 64;
        qf[mt][0] = *(const bf16x8*)(qbase + quad * 8);
        qf[mt][1] = *(const bf16x8*)(qbase + 32 + quad * 8);
    }

    floatx4 o[2][4];
#pragma unroll
    for (int mt = 0; mt < 2; ++mt)
#pragma unroll
        for (int i = 0; i < 4; i++) o[mt][i] = (floatx4)0.0f;
    float lacc[2] = {0.f, 0.f};

    const bf16_t* kb = K + ((size_t)bh * 2048) * 64;
    const bf16_t* vb = Vt + ((size_t)bh * 64) * 2048;

    // T15 pipeline state: previous tile's P fragments + V fragments (registers)
    bf16x8 pfragP[2], vfP[4];
    {
        uintx4 z; z.x = 0; z.y = 0; z.z = 0; z.w = 0;
        pfragP[0] = __builtin_bit_cast(bf16x8, z);
        pfragP[1] = __builtin_bit_cast(bf16x8, z);
#pragma unroll
        for (int sub = 0; sub < 4; ++sub) vfP[sub] = __builtin_bit_cast(bf16x8, z);
    }

    stage_tile(kb, vb, 0, Ks[0], Vs[0], wave, lane);

#pragma unroll 1
    for (int kt = 0; kt < 32; ++kt) {
        const int buf = kt & 1;
        __syncthreads();   // drains vmcnt (tile kt staged) + lgkmcnt (vfP ready)
        if (kt < 31)
            stage_tile(kb, vb, kt + 1, Ks[buf ^ 1], Vs[buf ^ 1], wave, lane);

        const bf16_t* ks = Ks[buf];
        const bf16_t* vs = Vs[buf];

        // S^T = K * Q^T : D[key=quad*4+r][q=c]; K rows via bw map.
        floatx4 s[2][2];
        __builtin_amdgcn_s_setprio(1);
#pragma unroll
        for (int nt = 0; nt < 2; ++nt) {
            const bf16_t* krow = ks + (khalf * 32 + nt * 16 + bw) * 64;
            bf16x8 kf0 = *(const bf16x8*)(krow + ((quad ^ brow7) << 3));
            bf16x8 kf1 = *(const bf16x8*)(krow + (((4 + quad) ^ brow7) << 3));
#pragma unroll
            for (int mt = 0; mt < 2; ++mt) {
                floatx4 t = (floatx4)0.0f;
                t = __builtin_amdgcn_mfma_f32_16x16x32_bf16(kf0, qf[mt][0], t, 0, 0, 0);
                t = __builtin_amdgcn_mfma_f32_16x16x32_bf16(kf1, qf[mt][1], t, 0, 0, 0);
                s[mt][nt] = t;
            }
        }
        // PV(kt-1): pure-register MFMAs — scheduler fills the exp2 window below
#pragma unroll
        for (int sub = 0; sub < 4; ++sub) {
            o[0][sub] = __builtin_amdgcn_mfma_f32_16x16x32_bf16(pfragP[0], vfP[sub], o[0][sub], 0, 0, 0);
            o[1][sub] = __builtin_amdgcn_mfma_f32_16x16x32_bf16(pfragP[1], vfP[sub], o[1][sub], 0, 0, 0);
        }
        __builtin_amdgcn_s_setprio(0);

        // P = exp2(S) -> pfragP (for next iteration's PV)
#pragma unroll
        for (int mt = 0; mt < 2; ++mt) {
            float pe[2][4];
#pragma unroll
            for (int nt = 0; nt < 2; ++nt)
#pragma unroll
                for (int r = 0; r < 4; ++r) {
                    float p = __builtin_amdgcn_exp2f(s[mt][nt][r]);
                    lacc[mt] += p;
                    pe[nt][r] = p;
                }
            unsigned A0 = pk2(pe[0][0], pe[0][1]);
            unsigned A1 = pk2(pe[0][2], pe[0][3]);
            unsigned B0 = pk2(pe[1][0], pe[1][1]);
            unsigned B1 = pk2(pe[1][2], pe[1][3]);
            auto r0 = __builtin_amdgcn_permlane32_swap((int)A0, (int)B0, false, false);
            auto r1 = __builtin_amdgcn_permlane32_swap((int)A1, (int)B1, false, false);
            uintx4 fd;
            fd.x = (unsigned)r0[0];
            fd.y = (unsigned)r1[0];
            fd.z = (unsigned)r0[1];
            fd.w = (unsigned)r1[1];
            pfragP[mt] = __builtin_bit_cast(bf16x8, fd);
        }

        // V fragments of THIS tile -> registers (consumed next iteration);
        // lgkm wait is absorbed by the next barrier's drain.
#pragma unroll
        for (int sub = 0; sub < 4; ++sub) {
            const bf16_t* vrow = vs + (sub * 16 + c) * 64;      // row&7 == t7
            vfP[sub] = *(const bf16x8*)(vrow + (((khalf * 4 + quad) ^ t7) << 3));
        }
    }

    // tail: PV(31)
    __builtin_amdgcn_s_setprio(1);
#pragma unroll
    for (int sub = 0; sub < 4; ++sub) {
        o[0][sub] = __builtin_amdgcn_mfma_f32_16x16x32_bf16(pfragP[0], vfP[sub], o[0][sub], 0, 0, 0);
        o[1][sub] = __builtin_amdgcn_mfma_f32_16x16x32_bf16(pfragP[1], vfP[sub], o[1][sub], 0, 0, 0);
    }
    __builtin_amdgcn_s_setprio(0);

    // in-wave reduction over the 4 key-quads: butterfly xor16 + xor32
#pragma unroll
    for (int mt = 0; mt < 2; ++mt) {
        lacc[mt] += __shfl_xor(lacc[mt], 16, 64);
        lacc[mt] += __shfl_xor(lacc[mt], 32, 64);
    }

    // cross-khalf reduction of partial O and l via LDS (once)
    __syncthreads();                 // all tile reads done; Ks/Vs reusable
    float* obuf = (float*)Ks;        // 2 qhalf x 2048 f32 = 16 KB
    float* lbuf = (float*)Vs;        // 2 qhalf x 32 f32
    if (khalf == 1) {
#pragma unroll
        for (int mt = 0; mt < 2; ++mt)
#pragma unroll
            for (int sub = 0; sub < 4; ++sub)
                *(floatx4*)(obuf + qhalf * 2048 + (mt * 4 + sub) * 256 + lane * 4) = o[mt][sub];
        if (lane < 16) {             // quad0 lanes: lacc holds l(q = mt*16+c)
#pragma unroll
            for (int mt = 0; mt < 2; ++mt)
                lbuf[qhalf * 32 + mt * 16 + c] = lacc[mt];
        }
    }
    __syncthreads();
    if (khalf == 0) {
#pragma unroll
        for (int mt = 0; mt < 2; ++mt)
#pragma unroll
            for (int sub = 0; sub < 4; ++sub)
                o[mt][sub] += *(const floatx4*)(obuf + qhalf * 2048 + (mt * 4 + sub) * 256 + lane * 4);
#pragma unroll
        for (int mt = 0; mt < 2; ++mt)
            lacc[mt] += lbuf[qhalf * 32 + mt * 16 + c];

        // epilogue: out[b][n][h*64 + d] = o / l ; l for row q=quad*4+r via shfl
        float* ob = Out + (size_t)b * 2048 * 512 + (size_t)h * 64;
#pragma unroll
        for (int mt = 0; mt < 2; ++mt) {
            int n0 = qt * 64 + qhalf * 32 + mt * 16 + quad * 4;
#pragma unroll
            for (int r = 0; r < 4; r++) {
                float lr = __shfl(lacc[mt], quad * 4 + r, 64);
                float inv = 1.0f / lr;
                float* orow = ob + (size_t)(n0 + r) * 512;
#pragma unroll
                for (int sub = 0; sub < 4; ++sub)
                    orow[sub * 16 + c] = o[mt][sub][r] * inv;
            }
        }
    }
}

// -------------------- launch --------------------
extern "C" void kernel_launch(void* const* d_in, const int* in_sizes, int n_in,
                              void* d_out, int out_size, void* d_ws, size_t ws_size,
                              hipStream_t stream) {
    const float* x = (const float*)d_in[0];   // [4,2048,512]
    const float* w = (const float*)d_in[1];   // [1536,512]
    float* out = (float*)d_out;               // [4,2048,512]

    char* ws = (char*)d_ws;
    bf16_t* xb = (bf16_t*)(ws);                       //  8 MB
    bf16_t* wb = (bf16_t*)(ws + 8388608);             //  1.5 MB
    bf16_t* q  = (bf16_t*)(ws + 9961472);             //  8 MB
    bf16_t* k  = (bf16_t*)(ws + 18350080);            //  8 MB
    bf16_t* vt = (bf16_t*)(ws + 26738688);            //  8 MB (end 33.5 MB)

    convert_kernel<<<4864, 256, 0, stream>>>(x, xb, w, wb, 1048576);
    qkv_gemm<<<1536, 256, 0, stream>>>(xb, wb, q, k, vt);
    flash_attn<<<dim3(32, 32), 256, 0, stream>>>(q, k, vt, out);
}

// Round 14
// 139.466 us; speedup vs baseline: 1.0160x; 1.0160x over previous
//
#include <hip/hip_runtime.h>
#include <hip/hip_bf16.h>
#include <stdint.h>

typedef __bf16 bf16_t;
typedef float floatx4 __attribute__((ext_vector_type(4)));
typedef __bf16 bf16x8 __attribute__((ext_vector_type(8)));
typedef __bf16 bf16x4 __attribute__((ext_vector_type(4)));
typedef unsigned int uintx4 __attribute__((ext_vector_type(4)));

// scale = DH^-0.5 * log2(e), folded into Q at GEMM epilogue so softmax uses raw exp2
#define QSCALE 0.1803368801111204f

// -------------------- async global->LDS (16B) --------------------
__device__ __forceinline__ void gl2lds16(const bf16_t* g, bf16_t* l) {
    __builtin_amdgcn_global_load_lds(
        (const __attribute__((address_space(1))) unsigned int*)g,
        (__attribute__((address_space(3))) unsigned int*)l,
        16, 0, 0);
}

// pack two f32 -> one dword of 2 bf16
__device__ __forceinline__ unsigned pk2(float lo, float hi) {
    unsigned short a = __builtin_bit_cast(unsigned short, (bf16_t)lo);
    unsigned short b = __builtin_bit_cast(unsigned short, (bf16_t)hi);
    return (unsigned)a | ((unsigned)b << 16);
}

// -------------------- fp32 -> bf16 convert (x and W fused) --------------------
__global__ __launch_bounds__(256) void convert_kernel(const float* __restrict__ x,
                                                      bf16_t* __restrict__ xb,
                                                      const float* __restrict__ w,
                                                      bf16_t* __restrict__ wb,
                                                      int nx4) {   // x chunks; W chunks follow
    int i = blockIdx.x * 256 + threadIdx.x;
    const float* in; bf16_t* out; int j;
    if (i < nx4) { in = x; out = xb; j = i; }
    else         { in = w; out = wb; j = i - nx4; }
    float4 v = ((const float4*)in)[j];
    bf16x4 o;
    o.x = (bf16_t)v.x; o.y = (bf16_t)v.y; o.z = (bf16_t)v.z; o.w = (bf16_t)v.w;
    ((bf16x4*)out)[j] = o;
}

// -------------------- QKV projection GEMM (gemm_bt) --------------------
// Session-best structure: 128x64 tile, double-buffered LDS, one barrier per
// K-step, gl2lds staging issued after the barrier / before compute, XCD
// swizzle. (R14/R15: reg-staged fp32 fusion is slower — m151; convert stays.)
__global__ __launch_bounds__(256, 3) void qkv_gemm(const bf16_t* __restrict__ X,   // [8192][512]
                                                   const bf16_t* __restrict__ W,   // [1536][512]
                                                   bf16_t* __restrict__ Q,         // [32][2048][64] (pre-scaled)
                                                   bf16_t* __restrict__ K,         // [32][2048][64]
                                                   bf16_t* __restrict__ Vt)        // [32][64][2048]
{
    __shared__ bf16_t As[2][128 * 64];   // 2 x 16 KB
    __shared__ bf16_t Bs[2][64 * 64];    // 2 x  8 KB   (total 48 KB -> 3 blocks/CU)

    const int tid  = threadIdx.x;
    const int wave = tid >> 6;
    const int lane = tid & 63;
    const int quad = lane >> 4;
    const int lrow = lane & 15;
    const int t7g  = lrow & 7;      // = row&7 of every fragment row this lane touches
    const int wbase = tid & 192;    // wave*64, wave-uniform

    int raw = blockIdx.x;
    int xcd = raw & 7;
    int idx = raw >> 3;
    int bx  = xcd * 8 + idx / 24;
    int by  = idx - (idx / 24) * 24;
    const int bm0 = bx * 128;
    const int bn0 = by * 64;
    const int mw = (wave >> 1) * 64;
    const int nw = (wave & 1) * 32;

    floatx4 acc[4][2];
#pragma unroll
    for (int i = 0; i < 4; i++)
#pragma unroll
        for (int j = 0; j < 2; j++) acc[i][j] = (floatx4)0.0f;

    const bf16_t* xb  = X + (size_t)bm0 * 512;
    const bf16_t* wbp = W + (size_t)bn0 * 512;
    const bf16_t* srcA[4];
    const bf16_t* srcB[2];
#pragma unroll
    for (int r = 0; r < 4; ++r) {
        int c = r * 256 + tid;
        int row = c >> 3, kc = c & 7;
        int skc = kc ^ (row & 7);              // swizzled source chunk
        srcA[r] = xb + (size_t)row * 512 + skc * 8;
    }
#pragma unroll
    for (int r = 0; r < 2; ++r) {
        int c = r * 256 + tid;
        int row = c >> 3, kc = c & 7;
        int skc = kc ^ (row & 7);
        srcB[r] = wbp + (size_t)row * 512 + skc * 8;
    }

    auto STAGE = [&](int bufI, int k0) {
#pragma unroll
        for (int r = 0; r < 4; ++r)
            gl2lds16(srcA[r] + k0, As[bufI] + (size_t)(r * 256 + wbase) * 8);
#pragma unroll
        for (int r = 0; r < 2; ++r)
            gl2lds16(srcB[r] + k0, Bs[bufI] + (size_t)(r * 256 + wbase) * 8);
    };

    STAGE(0, 0);

#pragma unroll 1
    for (int kb = 0; kb < 8; ++kb) {
        const int buf = kb & 1;
        __syncthreads();                 // drains vmcnt: tile kb staged; prev compute done
        if (kb < 7) STAGE(buf ^ 1, (kb + 1) * 64);

        const bf16_t* as = As[buf];
        const bf16_t* bs = Bs[buf];
#pragma unroll
        for (int ks = 0; ks < 2; ++ks) {
            bf16x8 af[4], bfr[2];
#pragma unroll
            for (int mi = 0; mi < 4; mi++)
                af[mi] = *(const bf16x8*)(as + (mw + mi * 16 + lrow) * 64 + (((ks * 4 + quad) ^ t7g) << 3));
#pragma unroll
            for (int ni = 0; ni < 2; ni++)
                bfr[ni] = *(const bf16x8*)(bs + (nw + ni * 16 + lrow) * 64 + (((ks * 4 + quad) ^ t7g) << 3));
            __builtin_amdgcn_s_setprio(1);
#pragma unroll
            for (int mi = 0; mi < 4; mi++)
#pragma unroll
                for (int ni = 0; ni < 2; ni++)
                    acc[mi][ni] = __builtin_amdgcn_mfma_f32_16x16x32_bf16(af[mi], bfr[ni], acc[mi][ni], 0, 0, 0);
            __builtin_amdgcn_s_setprio(0);
        }
    }

    // epilogue: C/D layout col=lane&15, row=quad*4+reg  [verified m89]
#pragma unroll
    for (int mi = 0; mi < 4; mi++) {
        int mbase = bm0 + mw + mi * 16 + quad * 4;
        int b = mbase >> 11, n = mbase & 2047;
#pragma unroll
        for (int ni = 0; ni < 2; ni++) {
            int o = bn0 + nw + ni * 16 + lrow;
            int s  = o >> 9;
            int h  = (o >> 6) & 7;
            int dh = o & 63;
            int bh = b * 8 + h;
            if (s == 2) {
                bf16x4 pv;
#pragma unroll
                for (int r = 0; r < 4; r++) pv[r] = (bf16_t)acc[mi][ni][r];
                *(bf16x4*)(Vt + ((size_t)bh * 64 + dh) * 2048 + n) = pv;   // 8B packed
            } else if (s == 0) {
#pragma unroll
                for (int r = 0; r < 4; r++)
                    Q[((size_t)bh * 2048 + n + r) * 64 + dh] = (bf16_t)(acc[mi][ni][r] * QSCALE);
            } else {
#pragma unroll
                for (int r = 0; r < 4; r++)
                    K[((size_t)bh * 2048 + n + r) * 64 + dh] = (bf16_t)acc[mi][ni][r];
            }
        }
    }
}

// -------------------- flash attention --------------------
// R8 structure — session optimum (9 structural variants R5-R17 all null or
// worse). Swapped QK^T (mfma(K,Q)) + quad-bit-swap K row map + permlane32_swap
// assemble PV A-frag in registers; P never touches LDS. No XCD swizzle
// (costs ~2.6us here). T15 cross-iter PV pipeline measured null (R17).
__device__ __forceinline__ void stage_tile(const bf16_t* __restrict__ kb,
                                           const bf16_t* __restrict__ vb,
                                           int kt, bf16_t* ksbuf, bf16_t* vsbuf,
                                           int wave, int lane) {
#pragma unroll
    for (int part = 0; part < 2; ++part) {
        int ch  = part * 256 + wave * 64 + lane;   // chunk id 0..511
        int row = ch >> 3, cc = ch & 7;
        int scc = cc ^ (row & 7);                  // swizzled source chunk
        bf16_t* ldst = ksbuf + (size_t)(part * 256 + wave * 64) * 8;  // wave-uniform
        gl2lds16(kb + ((size_t)(kt * 64 + row)) * 64 + scc * 8, ldst);
        bf16_t* ldst2 = vsbuf + (size_t)(part * 256 + wave * 64) * 8;
        gl2lds16(vb + (size_t)row * 2048 + kt * 64 + scc * 8, ldst2);
    }
}

__global__ __launch_bounds__(256, 5) void flash_attn(const bf16_t* __restrict__ Q,   // [32][2048][64], pre-scaled
                                                     const bf16_t* __restrict__ K,   // [32][2048][64]
                                                     const bf16_t* __restrict__ Vt,  // [32][64][2048]
                                                     float* __restrict__ Out)        // [4][2048][512]
{
    __shared__ bf16_t Ks[2][64 * 64];   // 16 KB
    __shared__ bf16_t Vs[2][64 * 64];   // 16 KB
    // total 32768 B -> 5 blocks/CU, 20 waves/CU

    const int tid  = threadIdx.x;
    const int wave = tid >> 6;
    const int lane = tid & 63;
    const int quad = lane >> 4;
    const int c    = lane & 15;
    const int t7   = c & 7;
    const int qhalf = wave >> 1;   // which 32 q-rows
    const int khalf = wave & 1;    // which 32 keys of each 64-key tile
    const int qt = blockIdx.x;
    const int bh = blockIdx.y;
    const int b = bh >> 3, h = bh & 7;

    // K A-operand row map: m=c -> key row bw = quad-bit-swapped c (bijective 0..15)
    const int bw    = ((c & 4) << 1) | ((c & 8) >> 1) | (c & 3);
    const int brow7 = bw & 7;

    // Q fragments (B-operand: n=lane&15=q-col, k=quad*8+j), shifted-query source row.
    bf16x8 qf[2][2];
#pragma unroll
    for (int mt = 0; mt < 2; ++mt) {
        int qg  = qt * 64 + qhalf * 32 + mt * 16 + c;
        int src = (qg == 0) ? 0 : qg - 1;
        const bf16_t* qbase = Q + ((size_t)bh * 2048 + src) * 64;
        qf[mt][0] = *(const bf16x8*)(qbase + quad * 8);
        qf[mt][1] = *(const bf16x8*)(qbase + 32 + quad * 8);
    }

    floatx4 o[2][4];
#pragma unroll
    for (int mt = 0; mt < 2; ++mt)
#pragma unroll
        for (int i = 0; i < 4; i++) o[mt][i] = (floatx4)0.0f;
    float lacc[2] = {0.f, 0.f};

    const bf16_t* kb = K + ((size_t)bh * 2048) * 64;
    const bf16_t* vb = Vt + ((size_t)bh * 64) * 2048;

    stage_tile(kb, vb, 0, Ks[0], Vs[0], wave, lane);

#pragma unroll 1
    for (int kt = 0; kt < 32; ++kt) {
        const int buf = kt & 1;
        __syncthreads();   // drains vmcnt: tile kt ready; all waves done reading buf^1
        if (kt < 31)
            stage_tile(kb, vb, kt + 1, Ks[buf ^ 1], Vs[buf ^ 1], wave, lane);

        const bf16_t* ks = Ks[buf];
        const bf16_t* vs = Vs[buf];

        // S^T = K * Q^T : D[key=quad*4+r][q=c]; K rows via bw map.
        floatx4 s[2][2];
        __builtin_amdgcn_s_setprio(1);
#pragma unroll
        for (int nt = 0; nt < 2; ++nt) {
            const bf16_t* krow = ks + (khalf * 32 + nt * 16 + bw) * 64;
            bf16x8 kf0 = *(const bf16x8*)(krow + ((quad ^ brow7) << 3));
            bf16x8 kf1 = *(const bf16x8*)(krow + (((4 + quad) ^ brow7) << 3));
#pragma unroll
            for (int mt = 0; mt < 2; ++mt) {
                floatx4 t = (floatx4)0.0f;
                t = __builtin_amdgcn_mfma_f32_16x16x32_bf16(kf0, qf[mt][0], t, 0, 0, 0);
                t = __builtin_amdgcn_mfma_f32_16x16x32_bf16(kf1, qf[mt][1], t, 0, 0, 0);
                s[mt][nt] = t;
            }
        }
        __builtin_amdgcn_s_setprio(0);

        // P = exp2(S); per-lane partial row sum (q=c); in-register PV A-frags
        bf16x8 pfrag[2];
#pragma unroll
        for (int mt = 0; mt < 2; ++mt) {
            float pe[2][4];
#pragma unroll
            for (int nt = 0; nt < 2; ++nt)
#pragma unroll
                for (int r = 0; r < 4; ++r) {
                    float p = __builtin_amdgcn_exp2f(s[mt][nt][r]);
                    lacc[mt] += p;
                    pe[nt][r] = p;
                }
            unsigned A0 = pk2(pe[0][0], pe[0][1]);
            unsigned A1 = pk2(pe[0][2], pe[0][3]);
            unsigned B0 = pk2(pe[1][0], pe[1][1]);
            unsigned B1 = pk2(pe[1][2], pe[1][3]);
            auto r0 = __builtin_amdgcn_permlane32_swap((int)A0, (int)B0, false, false);
            auto r1 = __builtin_amdgcn_permlane32_swap((int)A1, (int)B1, false, false);
            uintx4 fd;
            fd.x = (unsigned)r0[0];
            fd.y = (unsigned)r1[0];
            fd.z = (unsigned)r0[1];
            fd.w = (unsigned)r1[1];
            pfrag[mt] = __builtin_bit_cast(bf16x8, fd);
        }

        // O += P * V (contraction over this wave's 32 keys, A-frag in registers)
        __builtin_amdgcn_s_setprio(1);
#pragma unroll
        for (int sub = 0; sub < 4; ++sub) {
            const bf16_t* vrow = vs + (sub * 16 + c) * 64;      // row&7 == t7
            bf16x8 vf = *(const bf16x8*)(vrow + (((khalf * 4 + quad) ^ t7) << 3));
            o[0][sub] = __builtin_amdgcn_mfma_f32_16x16x32_bf16(pfrag[0], vf, o[0][sub], 0, 0, 0);
            o[1][sub] = __builtin_amdgcn_mfma_f32_16x16x32_bf16(pfrag[1], vf, o[1][sub], 0, 0, 0);
        }
        __builtin_amdgcn_s_setprio(0);
    }

    // in-wave reduction over the 4 key-quads: butterfly xor16 + xor32
#pragma unroll
    for (int mt = 0; mt < 2; ++mt) {
        lacc[mt] += __shfl_xor(lacc[mt], 16, 64);
        lacc[mt] += __shfl_xor(lacc[mt], 32, 64);
    }

    // cross-khalf reduction of partial O and l via LDS (once)
    __syncthreads();                 // all tile reads done; Ks/Vs reusable
    float* obuf = (float*)Ks;        // 2 qhalf x 2048 f32 = 16 KB
    float* lbuf = (float*)Vs;        // 2 qhalf x 32 f32
    if (khalf == 1) {
#pragma unroll
        for (int mt = 0; mt < 2; ++mt)
#pragma unroll
            for (int sub = 0; sub < 4; ++sub)
                *(floatx4*)(obuf + qhalf * 2048 + (mt * 4 + sub) * 256 + lane * 4) = o[mt][sub];
        if (lane < 16) {             // quad0 lanes: lacc holds l(q = mt*16+c)
#pragma unroll
            for (int mt = 0; mt < 2; ++mt)
                lbuf[qhalf * 32 + mt * 16 + c] = lacc[mt];
        }
    }
    __syncthreads();
    if (khalf == 0) {
#pragma unroll
        for (int mt = 0; mt < 2; ++mt)
#pragma unroll
            for (int sub = 0; sub < 4; ++sub)
                o[mt][sub] += *(const floatx4*)(obuf + qhalf * 2048 + (mt * 4 + sub) * 256 + lane * 4);
#pragma unroll
        for (int mt = 0; mt < 2; ++mt)
            lacc[mt] += lbuf[qhalf * 32 + mt * 16 + c];

        // epilogue: out[b][n][h*64 + d] = o / l ; l for row q=quad*4+r via shfl
        float* ob = Out + (size_t)b * 2048 * 512 + (size_t)h * 64;
#pragma unroll
        for (int mt = 0; mt < 2; ++mt) {
            int n0 = qt * 64 + qhalf * 32 + mt * 16 + quad * 4;
#pragma unroll
            for (int r = 0; r < 4; r++) {
                float lr = __shfl(lacc[mt], quad * 4 + r, 64);
                float inv = 1.0f / lr;
                float* orow = ob + (size_t)(n0 + r) * 512;
#pragma unroll
                for (int sub = 0; sub < 4; ++sub)
                    orow[sub * 16 + c] = o[mt][sub][r] * inv;
            }
        }
    }
}

// -------------------- launch --------------------
extern "C" void kernel_launch(void* const* d_in, const int* in_sizes, int n_in,
                              void* d_out, int out_size, void* d_ws, size_t ws_size,
                              hipStream_t stream) {
    const float* x = (const float*)d_in[0];   // [4,2048,512]
    const float* w = (const float*)d_in[1];   // [1536,512]
    float* out = (float*)d_out;               // [4,2048,512]

    char* ws = (char*)d_ws;
    bf16_t* xb = (bf16_t*)(ws);                       //  8 MB
    bf16_t* wb = (bf16_t*)(ws + 8388608);             //  1.5 MB
    bf16_t* q  = (bf16_t*)(ws + 9961472);             //  8 MB
    bf16_t* k  = (bf16_t*)(ws + 18350080);            //  8 MB
    bf16_t* vt = (bf16_t*)(ws + 26738688);            //  8 MB (end 33.5 MB)

    convert_kernel<<<4864, 256, 0, stream>>>(x, xb, w, wb, 1048576);
    qkv_gemm<<<1536, 256, 0, stream>>>(xb, wb, q, k, vt);
    flash_attn<<<dim3(32, 32), 256, 0, stream>>>(q, k, vt, out);
}